// Round 1
// 996.032 us; speedup vs baseline: 1.1592x; 1.1592x over previous
//
#include <hip/hip_runtime.h>

typedef unsigned short u16;
typedef __attribute__((ext_vector_type(8))) short short8;
typedef __attribute__((ext_vector_type(4))) float f32x4;

#define DE 512   // embed / model dim
#define SL 2048  // sequence length
#define NB 4     // batch
#define NH 8     // heads
#define HD 64    // head dim

__device__ __forceinline__ float bf2f(u16 h) {
    union { unsigned u; float f; } v; v.u = ((unsigned)h) << 16; return v.f;
}
__device__ __forceinline__ u16 f2bf(float f) {
    union { float f; unsigned u; } v; v.f = f;
    unsigned u = v.u;
    return (u16)((u + 0x7FFFu + ((u >> 16) & 1u)) >> 16);  // RNE
}
// load 8 consecutive fp32, round to bf16 fragment
__device__ __forceinline__ short8 ld8f(const float* __restrict__ p) {
    const float4 a = *(const float4*)p;
    const float4 b = *(const float4*)(p + 4);
    short8 r;
    ((u16*)&r)[0] = f2bf(a.x); ((u16*)&r)[1] = f2bf(a.y);
    ((u16*)&r)[2] = f2bf(a.z); ((u16*)&r)[3] = f2bf(a.w);
    ((u16*)&r)[4] = f2bf(b.x); ((u16*)&r)[5] = f2bf(b.y);
    ((u16*)&r)[6] = f2bf(b.z); ((u16*)&r)[7] = f2bf(b.w);
    return r;
}

// fp32 -> bf16 conversion pass; blockIdx.y selects one of 3 source arrays.
__global__ __launch_bounds__(256) void cvt3(const float* __restrict__ s0,
                                            const float* __restrict__ s1,
                                            const float* __restrict__ s2,
                                            u16* __restrict__ dst, int per) {
    const float* src = (blockIdx.y == 0) ? s0 : ((blockIdx.y == 1) ? s1 : s2);
    const int idx = (blockIdx.x * 256 + threadIdx.x) * 8;
    if (idx >= per) return;
    short8 v = ld8f(src + idx);
    *(short8*)(dst + (size_t)blockIdx.y * per + idx) = v;
}

// out[t][c] = sum_i X[t][i] * W[c][i] + bias[c];  M=8192 tokens, N=K=512.
// XBF/WBF: operand already bf16 (else fp32, converted inline). bias fp32.
// MODE 0: fp32 out, plain [t][512]
// MODE 1: bf16 out, head-split [b][h][t][64]
// MODE 2: bf16 out, head-split transposed [b][h][d][t]  (for V)
template <bool XBF, bool WBF, int MODE>
__global__ __launch_bounds__(256) void gemm512(const void* __restrict__ Xv,
                                               const void* __restrict__ Wv,
                                               const float* __restrict__ bias,
                                               void* __restrict__ outv) {
    const int lane = threadIdx.x & 63;
    const int wave = threadIdx.x >> 6;       // 0..3
    const int q16 = lane & 15, quad = lane >> 4;
    const int row0 = blockIdx.x * 64 + wave * 16;  // token tile (16 rows per wave)
    const int col0 = blockIdx.y * 64;              // output-channel tile

    f32x4 acc[4] = {};
    #pragma unroll 4
    for (int kk = 0; kk < DE; kk += 32) {
        short8 a;
        if (XBF)
            a = *(const short8*)((const u16*)Xv + (size_t)(row0 + q16) * DE + kk + quad * 8);
        else
            a = ld8f((const float*)Xv + (size_t)(row0 + q16) * DE + kk + quad * 8);
        #pragma unroll
        for (int ct = 0; ct < 4; ++ct) {
            short8 bw;
            if (WBF)
                bw = *(const short8*)((const u16*)Wv + (size_t)(col0 + ct * 16 + q16) * DE + kk + quad * 8);
            else
                bw = ld8f((const float*)Wv + (size_t)(col0 + ct * 16 + q16) * DE + kk + quad * 8);
            acc[ct] = __builtin_amdgcn_mfma_f32_16x16x32_bf16(a, bw, acc[ct], 0, 0, 0);
        }
    }

    #pragma unroll
    for (int ct = 0; ct < 4; ++ct) {
        const int col = col0 + ct * 16 + q16;        // C/D col = lane&15
        const float bv = bias[col];
        if (MODE == 2) {
            const int tg0 = row0 + quad * 4;         // 4 consecutive tokens (r=0..3)
            const int b = tg0 >> 11, t0 = tg0 & 2047;
            const int h = col >> 6, d = col & 63;
            ushort4 pk;
            pk.x = f2bf(acc[ct][0] + bv);
            pk.y = f2bf(acc[ct][1] + bv);
            pk.z = f2bf(acc[ct][2] + bv);
            pk.w = f2bf(acc[ct][3] + bv);
            *(ushort4*)((u16*)outv + ((size_t)((b * NH + h) * HD + d) << 11) + t0) = pk;
        } else if (MODE == 1) {
            const int h = col >> 6, d = col & 63;
            #pragma unroll
            for (int r = 0; r < 4; ++r) {
                const int tg = row0 + quad * 4 + r;  // C/D row = quad*4 + r
                const int b = tg >> 11, t = tg & 2047;
                ((u16*)outv)[(((size_t)(b * NH + h) * SL + t) << 6) + d] = f2bf(acc[ct][r] + bv);
            }
        } else {
            #pragma unroll
            for (int r = 0; r < 4; ++r) {
                const int tg = row0 + quad * 4 + r;
                ((float*)outv)[(size_t)tg * DE + col] = acc[ct][r] + bv;
            }
        }
    }
}

// One block: (b, h, 16 q-rows). 8 waves: phase1 each wave owns a 256-col k-strip,
// computing u=exp(s/8) (mask->0) into LDS (bf16) while accumulating row sums in
// registers. Tiny cross-wave reduce -> linv. Phase3 writes normalized attn fp32
// (nontemporal). Phase4 PV split-K: waves 0-3 k-lo, 4-7 k-hi, LDS combine.
__global__ __launch_bounds__(512) void attn_kernel(const u16* __restrict__ Q,
                                                   const u16* __restrict__ K,
                                                   const u16* __restrict__ Vt,
                                                   const int* __restrict__ mask,
                                                   float* __restrict__ attn_out,
                                                   u16* __restrict__ Obuf) {
    __shared__ __align__(16) u16 P[16][2056];   // 65,792 B (+8 pad)
    __shared__ float partial[16][8];
    __shared__ float linv[16];
    __shared__ float ored[4][16][16];           // 4 KB PV k-half combine

    const int tid = threadIdx.x;
    const int lane = tid & 63, wave = tid >> 6;  // 8 waves
    const int q16 = lane & 15, quad = lane >> 4;
    const int qblk = blockIdx.x, h = blockIdx.y, b = blockIdx.z;
    const int qbase = qblk * 16;

    const u16* qplane = Q + (size_t)((b * NH + h) * SL) * HD;
    const u16* kplane = K + (size_t)((b * NH + h) * SL) * HD;

    const u16* qrow = qplane + (qbase + q16) * HD + quad * 8;
    const short8 aq0 = *(const short8*)(qrow);
    const short8 aq1 = *(const short8*)(qrow + 32);

    // ---- Phase 1: S strip -> u = exp(s/8) (masked -> 0) into LDS + reg rowsums ----
    const int qg0 = qbase + quad * 4;                  // q row for r=0
    const int* mbase = mask + (size_t)(b * SL + qg0) * SL;
    const int k0 = wave * 256;
    float rs0 = 0.f, rs1 = 0.f, rs2 = 0.f, rs3 = 0.f;
    #pragma unroll 2
    for (int kt = 0; kt < 16; ++kt) {
        const int kbase = k0 + kt * 16;
        const u16* krow = kplane + (kbase + q16) * HD + quad * 8;
        short8 b0 = *(const short8*)(krow);
        short8 b1 = *(const short8*)(krow + 32);
        f32x4 s = {};
        s = __builtin_amdgcn_mfma_f32_16x16x32_bf16(aq0, b0, s, 0, 0, 0);
        s = __builtin_amdgcn_mfma_f32_16x16x32_bf16(aq1, b1, s, 0, 0, 0);
        const int* mrow = mbase + kbase + q16;
        const float u0 = mrow[0]          ? 0.0f : __expf(s[0] * 0.125f);
        const float u1 = mrow[SL]         ? 0.0f : __expf(s[1] * 0.125f);
        const float u2 = mrow[2 * SL]     ? 0.0f : __expf(s[2] * 0.125f);
        const float u3 = mrow[3 * SL]     ? 0.0f : __expf(s[3] * 0.125f);
        rs0 += u0; rs1 += u1; rs2 += u2; rs3 += u3;
        P[quad * 4 + 0][kbase + q16] = f2bf(u0);
        P[quad * 4 + 1][kbase + q16] = f2bf(u1);
        P[quad * 4 + 2][kbase + q16] = f2bf(u2);
        P[quad * 4 + 3][kbase + q16] = f2bf(u3);
    }
    // reduce row partials over the 16 q16 lanes (stays within each quad)
    #pragma unroll
    for (int off = 1; off < 16; off <<= 1) {
        rs0 += __shfl_xor(rs0, off);
        rs1 += __shfl_xor(rs1, off);
        rs2 += __shfl_xor(rs2, off);
        rs3 += __shfl_xor(rs3, off);
    }
    if (q16 == 0) {
        partial[quad * 4 + 0][wave] = rs0;
        partial[quad * 4 + 1][wave] = rs1;
        partial[quad * 4 + 2][wave] = rs2;
        partial[quad * 4 + 3][wave] = rs3;
    }
    __syncthreads();

    // ---- Phase 2: fold 8 strip-partials per row ----
    if (tid < 16) {
        float s = 0.f;
        #pragma unroll
        for (int w = 0; w < 8; ++w) s += partial[tid][w];
        linv[tid] = 1.0f / s;
    }
    __syncthreads();

    // ---- Phase 3: write normalized attn, fp32, nontemporal ----
    {
        const int r3 = tid >> 5, cseg = tid & 31;
        const float inv = linv[r3];
        const size_t rowbase = ((size_t)((b * NH + h) * SL + qbase + r3)) * SL;
        #pragma unroll
        for (int i = 0; i < 8; ++i) {
            const int c = cseg * 8 + i * 256;
            short8 v = *(const short8*)&P[r3][c];
            f32x4 w0, w1;
            w0[0] = bf2f(((u16*)&v)[0]) * inv;
            w0[1] = bf2f(((u16*)&v)[1]) * inv;
            w0[2] = bf2f(((u16*)&v)[2]) * inv;
            w0[3] = bf2f(((u16*)&v)[3]) * inv;
            w1[0] = bf2f(((u16*)&v)[4]) * inv;
            w1[1] = bf2f(((u16*)&v)[5]) * inv;
            w1[2] = bf2f(((u16*)&v)[6]) * inv;
            w1[3] = bf2f(((u16*)&v)[7]) * inv;
            __builtin_nontemporal_store(w0, (f32x4*)(attn_out + rowbase + c));
            __builtin_nontemporal_store(w1, (f32x4*)(attn_out + rowbase + c + 4));
        }
    }

    // ---- Phase 4: O = P @ V, split-K over wave halves ----
    const int dt = wave & 3, kh = wave >> 2;   // d-tile 0..3, k-half 0/1
    const u16* vplane = Vt + (size_t)((b * NH + h) * HD) * SL;
    f32x4 o = {};
    const int kstart = kh * 1024;
    #pragma unroll 4
    for (int kk = kstart; kk < kstart + 1024; kk += 32) {
        short8 a = *(const short8*)&P[q16][kk + quad * 8];
        short8 bv = *(const short8*)(vplane + (dt * 16 + q16) * SL + kk + quad * 8);
        o = __builtin_amdgcn_mfma_f32_16x16x32_bf16(a, bv, o, 0, 0, 0);
    }
    if (kh == 1) {
        #pragma unroll
        for (int rr = 0; rr < 4; ++rr) ored[dt][quad * 4 + rr][q16] = o[rr];
    }
    __syncthreads();
    if (kh == 0) {
        #pragma unroll
        for (int rr = 0; rr < 4; ++rr) {
            const int row = quad * 4 + rr;
            const float val = (o[rr] + ored[dt][row][q16]) * linv[row];
            const int qg = qbase + row;
            Obuf[(size_t)(b * SL + qg) * DE + h * HD + dt * 16 + q16] = f2bf(val);
        }
    }
}

extern "C" void kernel_launch(void* const* d_in, const int* in_sizes, int n_in,
                              void* d_out, int out_size, void* d_ws, size_t ws_size,
                              hipStream_t stream) {
    const float* x_q = (const float*)d_in[0];
    const float* x_k = (const float*)d_in[1];
    const float* x_v = (const float*)d_in[2];
    const int* mask = (const int*)d_in[3];
    const float* Wq = (const float*)d_in[4];
    const float* bq = (const float*)d_in[5];
    const float* Wk = (const float*)d_in[6];
    const float* bk = (const float*)d_in[7];
    const float* Wv = (const float*)d_in[8];
    const float* bv = (const float*)d_in[9];
    const float* Wo = (const float*)d_in[10];
    const float* bo = (const float*)d_in[11];

    // ws layout: q | k | vt | o_cat, each B*H*L*HD = 4,194,304 bf16 (8 MiB) -> 32 MiB
    u16* ws = (u16*)d_ws;
    u16* qb = ws;
    u16* kb = ws + 4194304;
    u16* vt = ws + 2 * 4194304;
    u16* ob = ws + 3 * 4194304;

    float* outp = (float*)d_out;
    float* attn_out = outp + 4194304;  // final is B*L*DE = 4,194,304 elems

    // Scratch for bf16 pre-converted X and W lives in the attn output region:
    // it is consumed by the QKV gemms (which run BEFORE attn_kernel), and
    // attn_kernel then overwrites every byte of this region with real output.
    u16* xbf = (u16*)attn_out;                 // 3 x 4,194,304 u16 (24 MiB)
    u16* wbf = xbf + 3 * 4194304;              // 3 x   262,144 u16 (1.5 MiB)

    cvt3<<<dim3(2048, 3), 256, 0, stream>>>(x_q, x_k, x_v, xbf, 4194304);
    cvt3<<<dim3(128, 3), 256, 0, stream>>>(Wq, Wk, Wv, wbf, 262144);

    dim3 gg(128, 8);
    gemm512<true, true, 1><<<gg, 256, 0, stream>>>(xbf, wbf, bq, qb);
    gemm512<true, true, 1><<<gg, 256, 0, stream>>>(xbf + 4194304, wbf + 262144, bk, kb);
    gemm512<true, true, 2><<<gg, 256, 0, stream>>>(xbf + 2 * 4194304, wbf + 2 * 262144, bv, vt);

    attn_kernel<<<dim3(128, 8, 4), 512, 0, stream>>>(qb, kb, vt, mask, attn_out, ob);

    // Final projection. Wo's bf16 copy must survive attn_kernel, so it needs
    // workspace: use it if the harness gave us >= 32 MiB + 512 KiB.
    if (ws_size >= (size_t)34078720) {
        u16* wobf = ws + 4 * 4194304;
        cvt3<<<dim3(128, 1), 256, 0, stream>>>(Wo, Wo, Wo, wobf, 262144);
        gemm512<true, true, 0><<<gg, 256, 0, stream>>>(ob, wobf, bo, outp);
    } else {
        gemm512<true, false, 0><<<gg, 256, 0, stream>>>(ob, Wo, bo, outp);
    }
}

// Round 2
// 891.001 us; speedup vs baseline: 1.2959x; 1.1179x over previous
//
#include <hip/hip_runtime.h>

typedef unsigned short u16;
typedef __attribute__((ext_vector_type(8))) short short8;
typedef __attribute__((ext_vector_type(4))) float f32x4;

#define DE 512   // embed / model dim
#define SL 2048  // sequence length
#define NB 4     // batch
#define NH 8     // heads
#define HD 64    // head dim

__device__ __forceinline__ float bf2f(u16 h) {
    union { unsigned u; float f; } v; v.u = ((unsigned)h) << 16; return v.f;
}
__device__ __forceinline__ u16 f2bf(float f) {
    union { float f; unsigned u; } v; v.f = f;
    unsigned u = v.u;
    return (u16)((u + 0x7FFFu + ((u >> 16) & 1u)) >> 16);  // RNE
}
// load 8 consecutive fp32, round to bf16 fragment
__device__ __forceinline__ short8 ld8f(const float* __restrict__ p) {
    const float4 a = *(const float4*)p;
    const float4 b = *(const float4*)(p + 4);
    short8 r;
    ((u16*)&r)[0] = f2bf(a.x); ((u16*)&r)[1] = f2bf(a.y);
    ((u16*)&r)[2] = f2bf(a.z); ((u16*)&r)[3] = f2bf(a.w);
    ((u16*)&r)[4] = f2bf(b.x); ((u16*)&r)[5] = f2bf(b.y);
    ((u16*)&r)[6] = f2bf(b.z); ((u16*)&r)[7] = f2bf(b.w);
    return r;
}

// fp32 -> bf16 conversion pass; blockIdx.y selects one of 3 source arrays.
__global__ __launch_bounds__(256) void cvt3(const float* __restrict__ s0,
                                            const float* __restrict__ s1,
                                            const float* __restrict__ s2,
                                            u16* __restrict__ dst, int per) {
    const float* src = (blockIdx.y == 0) ? s0 : ((blockIdx.y == 1) ? s1 : s2);
    const int idx = (blockIdx.x * 256 + threadIdx.x) * 8;
    if (idx >= per) return;
    short8 v = ld8f(src + idx);
    *(short8*)(dst + (size_t)blockIdx.y * per + idx) = v;
}

// async 16B global -> LDS
__device__ __forceinline__ void llds16(const u16* g, u16* l) {
    __builtin_amdgcn_global_load_lds((const __attribute__((address_space(1))) void*)g,
                                     (__attribute__((address_space(3))) void*)l, 16, 0, 0);
}

// ---------------- LDS-staged 128x128 GEMM (bf16 MFMA) ----------------
// C[t][c] = sum_k X[t][k] * W[c][k] + bias[c]; X [8192][512], W [512][512], bf16.
// 256 threads = 4 waves; wave w owns 64x64 (wr=w>>1, wc=w&1); BK=64, dbuf LDS.
// LDS tiles stored with XOR swizzle: phys_col_byte = logical_k_byte ^ ((row&7)<<4).
// global_load_lds writes linear dest (tid*16), so the SOURCE k-offset is
// pre-swizzled; ds_read_b128 applies the same XOR -> conflict-free stride-128B reads.
// MODE 0: fp32 out [t][512]; MODE 1: bf16 head-split [b][h][t][64];
// MODE 2: bf16 head-split transposed [b][h][d][t].
template <int MODE>
__global__ __launch_bounds__(256, 1) void gemm_lds(const u16* __restrict__ X,
                                                   const u16* __restrict__ W,
                                                   const float* __restrict__ bias,
                                                   void* __restrict__ outv) {
    __shared__ __align__(16) u16 As[2][8192];   // 128 rows x 64 k, 16 KB each
    __shared__ __align__(16) u16 Bs[2][8192];

    const int tid = threadIdx.x;
    const int l = tid & 63, w = tid >> 6;
    const int q16 = l & 15, quad = l >> 4;
    const int tok0 = blockIdx.x * 128;
    const int col0 = blockIdx.y * 128;
    const int wr = w >> 1, wc = w & 1;

    // staging: pass i stages rows r = i*32 + w*8 + (l>>3), 16B chunk (l&7) of the row;
    // LDS dest byte = i*4096 + w*1024 + l*16  (wave-uniform base + lane*16).
    // source chunk is pre-swizzled: chunk_src = (l&7) ^ (l>>3)  ( == (l&7) ^ (r&7) ).
    const int srow = w * 8 + (l >> 3);
    const int scol = ((l & 7) ^ (l >> 3)) * 8;          // u16 units
    const u16* ga = X + (size_t)(tok0 + srow) * DE + scol;
    const u16* gb = W + (size_t)(col0 + srow) * DE + scol;
    u16* la0 = &As[0][tid * 8]; u16* la1 = &As[1][tid * 8];
    u16* lb0 = &Bs[0][tid * 8]; u16* lb1 = &Bs[1][tid * 8];

    f32x4 acc[4][4] = {};

    // prologue: stage tile 0 into buf 0
    #pragma unroll
    for (int i = 0; i < 4; ++i) {
        llds16(ga + (size_t)i * 32 * DE, la0 + i * 2048);
        llds16(gb + (size_t)i * 32 * DE, lb0 + i * 2048);
    }
    __syncthreads();

    int cur = 0;
    for (int ks = 64; ks <= DE; ks += 64) {
        if (ks < DE) {      // stage next tile into the other buffer
            u16* da = cur ? la0 : la1;
            u16* db = cur ? lb0 : lb1;
            #pragma unroll
            for (int i = 0; i < 4; ++i) {
                llds16(ga + (size_t)i * 32 * DE + ks, da + i * 2048);
                llds16(gb + (size_t)i * 32 * DE + ks, db + i * 2048);
            }
        }
        // compute on buf cur
        const char* Ab = (const char*)As[cur];
        const char* Bb = (const char*)Bs[cur];
        #pragma unroll
        for (int kk = 0; kk < 64; kk += 32) {
            short8 af[4], bf[4];
            #pragma unroll
            for (int m = 0; m < 4; ++m) {
                const int row = wr * 64 + m * 16 + q16;
                const int byt = row * 128 + (((kk + quad * 8) * 2) ^ ((q16 & 7) << 4));
                af[m] = *(const short8*)(Ab + byt);
            }
            #pragma unroll
            for (int n = 0; n < 4; ++n) {
                const int row = wc * 64 + n * 16 + q16;
                const int byt = row * 128 + (((kk + quad * 8) * 2) ^ ((q16 & 7) << 4));
                bf[n] = *(const short8*)(Bb + byt);
            }
            #pragma unroll
            for (int m = 0; m < 4; ++m)
                #pragma unroll
                for (int n = 0; n < 4; ++n)
                    acc[m][n] = __builtin_amdgcn_mfma_f32_16x16x32_bf16(af[m], bf[n], acc[m][n], 0, 0, 0);
        }
        __syncthreads();    // drains vmcnt(0): next tile's stage complete
        cur ^= 1;
    }

    #pragma unroll
    for (int n = 0; n < 4; ++n) {
        const int col = col0 + wc * 64 + n * 16 + q16;   // C/D col = lane&15
        const float bv = bias[col];
        #pragma unroll
        for (int m = 0; m < 4; ++m) {
            const f32x4 a4 = acc[m][n];
            const int tg0 = tok0 + wr * 64 + m * 16 + quad * 4;  // C/D row = quad*4+r
            if (MODE == 2) {
                const int b = tg0 >> 11, t0 = tg0 & 2047;
                const int h = col >> 6, d = col & 63;
                ushort4 pk;
                pk.x = f2bf(a4[0] + bv); pk.y = f2bf(a4[1] + bv);
                pk.z = f2bf(a4[2] + bv); pk.w = f2bf(a4[3] + bv);
                *(ushort4*)((u16*)outv + ((size_t)((b * NH + h) * HD + d) << 11) + t0) = pk;
            } else if (MODE == 1) {
                const int h = col >> 6, d = col & 63;
                #pragma unroll
                for (int r = 0; r < 4; ++r) {
                    const int tg = tg0 + r;
                    const int b = tg >> 11, t = tg & 2047;
                    ((u16*)outv)[(((size_t)(b * NH + h) * SL + t) << 6) + d] = f2bf(a4[r] + bv);
                }
            } else {
                #pragma unroll
                for (int r = 0; r < 4; ++r)
                    ((float*)outv)[(size_t)(tg0 + r) * DE + col] = a4[r] + bv;
            }
        }
    }
}

// Fallback final-projection gemm (fp32 W converted inline) if workspace is tight.
template <bool XBF, bool WBF, int MODE>
__global__ __launch_bounds__(256) void gemm512(const void* __restrict__ Xv,
                                               const void* __restrict__ Wv,
                                               const float* __restrict__ bias,
                                               void* __restrict__ outv) {
    const int lane = threadIdx.x & 63;
    const int wave = threadIdx.x >> 6;
    const int q16 = lane & 15, quad = lane >> 4;
    const int row0 = blockIdx.x * 64 + wave * 16;
    const int col0 = blockIdx.y * 64;

    f32x4 acc[4] = {};
    #pragma unroll 4
    for (int kk = 0; kk < DE; kk += 32) {
        short8 a;
        if (XBF)
            a = *(const short8*)((const u16*)Xv + (size_t)(row0 + q16) * DE + kk + quad * 8);
        else
            a = ld8f((const float*)Xv + (size_t)(row0 + q16) * DE + kk + quad * 8);
        #pragma unroll
        for (int ct = 0; ct < 4; ++ct) {
            short8 bw;
            if (WBF)
                bw = *(const short8*)((const u16*)Wv + (size_t)(col0 + ct * 16 + q16) * DE + kk + quad * 8);
            else
                bw = ld8f((const float*)Wv + (size_t)(col0 + ct * 16 + q16) * DE + kk + quad * 8);
            acc[ct] = __builtin_amdgcn_mfma_f32_16x16x32_bf16(a, bw, acc[ct], 0, 0, 0);
        }
    }
    #pragma unroll
    for (int ct = 0; ct < 4; ++ct) {
        const int col = col0 + ct * 16 + q16;
        const float bv = bias[col];
        #pragma unroll
        for (int r = 0; r < 4; ++r) {
            const int tg = row0 + quad * 4 + r;
            ((float*)outv)[(size_t)tg * DE + col] = acc[ct][r] + bv;
        }
    }
}

// One block: (b, h, 16 q-rows). 8 waves: phase1 each wave owns a 256-col k-strip,
// computing u=exp(s/8) (mask->0) into LDS (bf16) while accumulating row sums in
// registers. Tiny cross-wave reduce -> linv. Phase3 writes normalized attn fp32
// (nontemporal). Phase4 PV split-K: waves 0-3 k-lo, 4-7 k-hi, LDS combine.
__global__ __launch_bounds__(512) void attn_kernel(const u16* __restrict__ Q,
                                                   const u16* __restrict__ K,
                                                   const u16* __restrict__ Vt,
                                                   const int* __restrict__ mask,
                                                   float* __restrict__ attn_out,
                                                   u16* __restrict__ Obuf) {
    __shared__ __align__(16) u16 P[16][2056];   // 65,792 B (+8 pad)
    __shared__ float partial[16][8];
    __shared__ float linv[16];
    __shared__ float ored[4][16][16];           // 4 KB PV k-half combine

    const int tid = threadIdx.x;
    const int lane = tid & 63, wave = tid >> 6;  // 8 waves
    const int q16 = lane & 15, quad = lane >> 4;
    const int qblk = blockIdx.x, h = blockIdx.y, b = blockIdx.z;
    const int qbase = qblk * 16;

    const u16* qplane = Q + (size_t)((b * NH + h) * SL) * HD;
    const u16* kplane = K + (size_t)((b * NH + h) * SL) * HD;

    const u16* qrow = qplane + (qbase + q16) * HD + quad * 8;
    const short8 aq0 = *(const short8*)(qrow);
    const short8 aq1 = *(const short8*)(qrow + 32);

    // ---- Phase 1: S strip -> u = exp(s/8) (masked -> 0) into LDS + reg rowsums ----
    const int qg0 = qbase + quad * 4;                  // q row for r=0
    const int* mbase = mask + (size_t)(b * SL + qg0) * SL;
    const int k0 = wave * 256;
    float rs0 = 0.f, rs1 = 0.f, rs2 = 0.f, rs3 = 0.f;
    #pragma unroll 2
    for (int kt = 0; kt < 16; ++kt) {
        const int kbase = k0 + kt * 16;
        const u16* krow = kplane + (kbase + q16) * HD + quad * 8;
        short8 b0 = *(const short8*)(krow);
        short8 b1 = *(const short8*)(krow + 32);
        f32x4 s = {};
        s = __builtin_amdgcn_mfma_f32_16x16x32_bf16(aq0, b0, s, 0, 0, 0);
        s = __builtin_amdgcn_mfma_f32_16x16x32_bf16(aq1, b1, s, 0, 0, 0);
        const int* mrow = mbase + kbase + q16;
        const float u0 = mrow[0]          ? 0.0f : __expf(s[0] * 0.125f);
        const float u1 = mrow[SL]         ? 0.0f : __expf(s[1] * 0.125f);
        const float u2 = mrow[2 * SL]     ? 0.0f : __expf(s[2] * 0.125f);
        const float u3 = mrow[3 * SL]     ? 0.0f : __expf(s[3] * 0.125f);
        rs0 += u0; rs1 += u1; rs2 += u2; rs3 += u3;
        P[quad * 4 + 0][kbase + q16] = f2bf(u0);
        P[quad * 4 + 1][kbase + q16] = f2bf(u1);
        P[quad * 4 + 2][kbase + q16] = f2bf(u2);
        P[quad * 4 + 3][kbase + q16] = f2bf(u3);
    }
    // reduce row partials over the 16 q16 lanes (stays within each quad)
    #pragma unroll
    for (int off = 1; off < 16; off <<= 1) {
        rs0 += __shfl_xor(rs0, off);
        rs1 += __shfl_xor(rs1, off);
        rs2 += __shfl_xor(rs2, off);
        rs3 += __shfl_xor(rs3, off);
    }
    if (q16 == 0) {
        partial[quad * 4 + 0][wave] = rs0;
        partial[quad * 4 + 1][wave] = rs1;
        partial[quad * 4 + 2][wave] = rs2;
        partial[quad * 4 + 3][wave] = rs3;
    }
    __syncthreads();

    // ---- Phase 2: fold 8 strip-partials per row ----
    if (tid < 16) {
        float s = 0.f;
        #pragma unroll
        for (int w = 0; w < 8; ++w) s += partial[tid][w];
        linv[tid] = 1.0f / s;
    }
    __syncthreads();

    // ---- Phase 3: write normalized attn, fp32, nontemporal ----
    {
        const int r3 = tid >> 5, cseg = tid & 31;
        const float inv = linv[r3];
        const size_t rowbase = ((size_t)((b * NH + h) * SL + qbase + r3)) * SL;
        #pragma unroll
        for (int i = 0; i < 8; ++i) {
            const int c = cseg * 8 + i * 256;
            short8 v = *(const short8*)&P[r3][c];
            f32x4 w0, w1;
            w0[0] = bf2f(((u16*)&v)[0]) * inv;
            w0[1] = bf2f(((u16*)&v)[1]) * inv;
            w0[2] = bf2f(((u16*)&v)[2]) * inv;
            w0[3] = bf2f(((u16*)&v)[3]) * inv;
            w1[0] = bf2f(((u16*)&v)[4]) * inv;
            w1[1] = bf2f(((u16*)&v)[5]) * inv;
            w1[2] = bf2f(((u16*)&v)[6]) * inv;
            w1[3] = bf2f(((u16*)&v)[7]) * inv;
            __builtin_nontemporal_store(w0, (f32x4*)(attn_out + rowbase + c));
            __builtin_nontemporal_store(w1, (f32x4*)(attn_out + rowbase + c + 4));
        }
    }

    // ---- Phase 4: O = P @ V, split-K over wave halves ----
    const int dt = wave & 3, kh = wave >> 2;   // d-tile 0..3, k-half 0/1
    const u16* vplane = Vt + (size_t)((b * NH + h) * HD) * SL;
    f32x4 o = {};
    const int kstart = kh * 1024;
    #pragma unroll 4
    for (int kk = kstart; kk < kstart + 1024; kk += 32) {
        short8 a = *(const short8*)&P[q16][kk + quad * 8];
        short8 bv = *(const short8*)(vplane + (dt * 16 + q16) * SL + kk + quad * 8);
        o = __builtin_amdgcn_mfma_f32_16x16x32_bf16(a, bv, o, 0, 0, 0);
    }
    if (kh == 1) {
        #pragma unroll
        for (int rr = 0; rr < 4; ++rr) ored[dt][quad * 4 + rr][q16] = o[rr];
    }
    __syncthreads();
    if (kh == 0) {
        #pragma unroll
        for (int rr = 0; rr < 4; ++rr) {
            const int row = quad * 4 + rr;
            const float val = (o[rr] + ored[dt][row][q16]) * linv[row];
            const int qg = qbase + row;
            Obuf[(size_t)(b * SL + qg) * DE + h * HD + dt * 16 + q16] = f2bf(val);
        }
    }
}

extern "C" void kernel_launch(void* const* d_in, const int* in_sizes, int n_in,
                              void* d_out, int out_size, void* d_ws, size_t ws_size,
                              hipStream_t stream) {
    const float* x_q = (const float*)d_in[0];
    const float* x_k = (const float*)d_in[1];
    const float* x_v = (const float*)d_in[2];
    const int* mask = (const int*)d_in[3];
    const float* Wq = (const float*)d_in[4];
    const float* bq = (const float*)d_in[5];
    const float* Wk = (const float*)d_in[6];
    const float* bk = (const float*)d_in[7];
    const float* Wv = (const float*)d_in[8];
    const float* bv = (const float*)d_in[9];
    const float* Wo = (const float*)d_in[10];
    const float* bo = (const float*)d_in[11];

    // ws layout: q | k | vt | o_cat, each B*H*L*HD = 4,194,304 bf16 (8 MiB) -> 32 MiB
    u16* ws = (u16*)d_ws;
    u16* qb = ws;
    u16* kb = ws + 4194304;
    u16* vt = ws + 2 * 4194304;
    u16* ob = ws + 3 * 4194304;

    float* outp = (float*)d_out;
    float* attn_out = outp + 4194304;  // final is B*L*DE = 4,194,304 elems

    // Scratch for bf16 pre-converted X and W lives in the attn output region:
    // it is consumed by the QKV gemms (which run BEFORE attn_kernel), and
    // attn_kernel then overwrites every byte of this region with real output.
    u16* xbf = (u16*)attn_out;                 // 3 x 4,194,304 u16 (24 MiB)
    u16* wbf = xbf + 3 * 4194304;              // 3 x   262,144 u16 (1.5 MiB)

    cvt3<<<dim3(2048, 3), 256, 0, stream>>>(x_q, x_k, x_v, xbf, 4194304);
    cvt3<<<dim3(128, 3), 256, 0, stream>>>(Wq, Wk, Wv, wbf, 262144);

    dim3 gl(64, 4);   // 8192/128 x 512/128
    gemm_lds<1><<<gl, 256, 0, stream>>>(xbf, wbf, bq, qb);
    gemm_lds<1><<<gl, 256, 0, stream>>>(xbf + 4194304, wbf + 262144, bk, kb);
    gemm_lds<2><<<gl, 256, 0, stream>>>(xbf + 2 * 4194304, wbf + 2 * 262144, bv, vt);

    attn_kernel<<<dim3(128, 8, 4), 512, 0, stream>>>(qb, kb, vt, mask, attn_out, ob);

    // Final projection. Wo's bf16 copy must survive attn_kernel, so it needs
    // workspace: use it if the harness gave us >= 32 MiB + 512 KiB.
    if (ws_size >= (size_t)34078720) {
        u16* wobf = ws + 4 * 4194304;
        cvt3<<<dim3(128, 1), 256, 0, stream>>>(Wo, Wo, Wo, wobf, 262144);
        gemm_lds<0><<<gl, 256, 0, stream>>>(ob, wobf, bo, outp);
    } else {
        gemm512<true, false, 0><<<dim3(128, 8), 256, 0, stream>>>(ob, Wo, bo, outp);
    }
}

// Round 3
// 880.089 us; speedup vs baseline: 1.3120x; 1.0124x over previous
//
#include <hip/hip_runtime.h>

typedef unsigned short u16;
typedef __attribute__((ext_vector_type(8))) short short8;
typedef __attribute__((ext_vector_type(4))) float f32x4;

#define DE 512   // embed / model dim
#define SL 2048  // sequence length
#define NB 4     // batch
#define NH 8     // heads
#define HD 64    // head dim

__device__ __forceinline__ float bf2f(u16 h) {
    union { unsigned u; float f; } v; v.u = ((unsigned)h) << 16; return v.f;
}
__device__ __forceinline__ u16 f2bf(float f) {
    union { float f; unsigned u; } v; v.f = f;
    unsigned u = v.u;
    return (u16)((u + 0x7FFFu + ((u >> 16) & 1u)) >> 16);  // RNE
}
// load 8 consecutive fp32, round to bf16 fragment
__device__ __forceinline__ short8 ld8f(const float* __restrict__ p) {
    const float4 a = *(const float4*)p;
    const float4 b = *(const float4*)(p + 4);
    short8 r;
    ((u16*)&r)[0] = f2bf(a.x); ((u16*)&r)[1] = f2bf(a.y);
    ((u16*)&r)[2] = f2bf(a.z); ((u16*)&r)[3] = f2bf(a.w);
    ((u16*)&r)[4] = f2bf(b.x); ((u16*)&r)[5] = f2bf(b.y);
    ((u16*)&r)[6] = f2bf(b.z); ((u16*)&r)[7] = f2bf(b.w);
    return r;
}

// fp32 -> bf16 conversion pass; blockIdx.y selects one of 3 source arrays.
__global__ __launch_bounds__(256) void cvt3(const float* __restrict__ s0,
                                            const float* __restrict__ s1,
                                            const float* __restrict__ s2,
                                            u16* __restrict__ dst, int per) {
    const float* src = (blockIdx.y == 0) ? s0 : ((blockIdx.y == 1) ? s1 : s2);
    const int idx = (blockIdx.x * 256 + threadIdx.x) * 8;
    if (idx >= per) return;
    short8 v = ld8f(src + idx);
    *(short8*)(dst + (size_t)blockIdx.y * per + idx) = v;
}

// async 16B global -> LDS
__device__ __forceinline__ void llds16(const u16* g, u16* l) {
    __builtin_amdgcn_global_load_lds((const __attribute__((address_space(1))) void*)g,
                                     (__attribute__((address_space(3))) void*)l, 16, 0, 0);
}

// ---------------- 64x64-tile LDS-staged GEMM body (bf16 MFMA) ----------------
// C[t][c] = sum_k X[t][k]*W[c][k] + bias[c], K = 512, bf16 inputs.
// 256 threads = 4 waves; wave w owns 32x32 (wr=w>>1, wc=w&1); BK=64, dbuf LDS.
// LDS 32 KB/block -> ~5 blocks/CU resident: latency hidden by TLP (small-shape
// regime; 128^2 tiles gave a 256-block grid = 1 wave/SIMD and ran 25x off peak).
// XOR swizzle, both sides (rule 21): linear LDS dest (tid*16B), pre-swizzled
// global source chunk ( (tid&7) ^ (row&7) ), swizzled ds_read. Conflict-free.
// mode 0: fp32 out [t][512]; mode 1: bf16 head-split [b][h][t][64];
// mode 2: bf16 head-split transposed [b][h][d][t].
__device__ __forceinline__ void gemm64_body(u16* As, u16* Bs,   // each [2][4096] u16
                                            const u16* __restrict__ X,
                                            const u16* __restrict__ W,
                                            const float* __restrict__ bias,
                                            void* __restrict__ outv,
                                            int mode, int tok0, int col0) {
    const int tid = threadIdx.x;
    const int l = tid & 63, w = tid >> 6;
    const int q16 = l & 15, quad = l >> 4;
    const int wr = w >> 1, wc = w & 1;

    // staging: pass i stages rows r = i*32 + (tid>>3); 16B chunk (tid&7) of row.
    // LDS dest byte = i*4096 + tid*16 (wave-uniform base + lane*16).
    const int srow = tid >> 3;                          // 0..31
    const int scol = ((tid & 7) ^ (srow & 7)) * 8;      // u16 units, pre-swizzled
    const u16* ga = X + (size_t)(tok0 + srow) * DE + scol;
    const u16* gb = W + (size_t)(col0 + srow) * DE + scol;
    u16* la = As + tid * 8;
    u16* lb = Bs + tid * 8;

    f32x4 acc[2][2] = {};

    // prologue: stage tile 0 into buf 0
    #pragma unroll
    for (int i = 0; i < 2; ++i) {
        llds16(ga + (size_t)i * 32 * DE, la + i * 2048);
        llds16(gb + (size_t)i * 32 * DE, lb + i * 2048);
    }
    __syncthreads();

    int cur = 0;
    for (int ks = 64; ks <= DE; ks += 64) {
        if (ks < DE) {      // stage next tile into the other buffer
            u16* da = la + (cur ^ 1) * 4096;
            u16* db = lb + (cur ^ 1) * 4096;
            #pragma unroll
            for (int i = 0; i < 2; ++i) {
                llds16(ga + (size_t)i * 32 * DE + ks, da + i * 2048);
                llds16(gb + (size_t)i * 32 * DE + ks, db + i * 2048);
            }
        }
        const char* Ab = (const char*)(As + cur * 4096);
        const char* Bb = (const char*)(Bs + cur * 4096);
        #pragma unroll
        for (int kk = 0; kk < 64; kk += 32) {
            short8 af[2], bf[2];
            #pragma unroll
            for (int m = 0; m < 2; ++m) {
                const int row = wr * 32 + m * 16 + q16;
                af[m] = *(const short8*)(Ab + row * 128 + (((kk + quad * 8) * 2) ^ ((q16 & 7) << 4)));
            }
            #pragma unroll
            for (int n = 0; n < 2; ++n) {
                const int row = wc * 32 + n * 16 + q16;
                bf[n] = *(const short8*)(Bb + row * 128 + (((kk + quad * 8) * 2) ^ ((q16 & 7) << 4)));
            }
            #pragma unroll
            for (int m = 0; m < 2; ++m)
                #pragma unroll
                for (int n = 0; n < 2; ++n)
                    acc[m][n] = __builtin_amdgcn_mfma_f32_16x16x32_bf16(af[m], bf[n], acc[m][n], 0, 0, 0);
        }
        __syncthreads();    // next tile staged (vmcnt drained) + buffer reuse safe
        cur ^= 1;
    }

    #pragma unroll
    for (int n = 0; n < 2; ++n) {
        const int col = col0 + wc * 32 + n * 16 + q16;   // C/D col = lane&15
        const float bv = bias[col];
        #pragma unroll
        for (int m = 0; m < 2; ++m) {
            const f32x4 a4 = acc[m][n];
            const int tg0 = tok0 + wr * 32 + m * 16 + quad * 4;  // C/D row = quad*4+r
            if (mode == 2) {
                const int b = tg0 >> 11, t0 = tg0 & 2047;
                const int h = col >> 6, d = col & 63;
                ushort4 pk;
                pk.x = f2bf(a4[0] + bv); pk.y = f2bf(a4[1] + bv);
                pk.z = f2bf(a4[2] + bv); pk.w = f2bf(a4[3] + bv);
                *(ushort4*)((u16*)outv + ((size_t)((b * NH + h) * HD + d) << 11) + t0) = pk;
            } else if (mode == 1) {
                const int h = col >> 6, d = col & 63;
                #pragma unroll
                for (int r = 0; r < 4; ++r) {
                    const int tg = tg0 + r;
                    const int b = tg >> 11, t = tg & 2047;
                    ((u16*)outv)[(((size_t)(b * NH + h) * SL + t) << 6) + d] = f2bf(a4[r] + bv);
                }
            } else {
                #pragma unroll
                for (int r = 0; r < 4; ++r)
                    ((float*)outv)[(size_t)(tg0 + r) * DE + col] = a4[r] + bv;
            }
        }
    }
}

// Fused Q/K/V projection: blockIdx.z selects which gemm. xbf/wbf/out are
// contiguous by z, so one dispatch carries 3072 blocks (vs 3x256 before).
__global__ __launch_bounds__(256) void gemm_qkv(const u16* __restrict__ xbf,
                                                const u16* __restrict__ wbf,
                                                const float* __restrict__ bq,
                                                const float* __restrict__ bk,
                                                const float* __restrict__ bv,
                                                u16* __restrict__ outbase) {
    __shared__ __align__(16) u16 As[2][4096];
    __shared__ __align__(16) u16 Bs[2][4096];
    const int z = blockIdx.z;
    const u16* X = xbf + (size_t)z * 4194304;
    const u16* W = wbf + (size_t)z * 262144;
    const float* bias = (z == 0) ? bq : ((z == 1) ? bk : bv);
    u16* out = outbase + (size_t)z * 4194304;
    gemm64_body(&As[0][0], &Bs[0][0], X, W, bias, out,
                (z == 2) ? 2 : 1, blockIdx.x * 64, blockIdx.y * 64);
}

// Final projection: bf16 O-concat @ Wo^T + bo -> fp32 out.
__global__ __launch_bounds__(256) void gemm_fin(const u16* __restrict__ X,
                                                const u16* __restrict__ W,
                                                const float* __restrict__ bias,
                                                float* __restrict__ outp) {
    __shared__ __align__(16) u16 As[2][4096];
    __shared__ __align__(16) u16 Bs[2][4096];
    gemm64_body(&As[0][0], &Bs[0][0], X, W, bias, outp,
                0, blockIdx.x * 64, blockIdx.y * 64);
}

// One block: (b, h, 16 q-rows). 8 waves: phase1 each wave owns a 256-col k-strip,
// computing u=exp(s/8) (mask->0) into LDS (bf16) while accumulating row sums in
// registers. Tiny cross-wave reduce -> linv. Phase3 writes normalized attn fp32
// (nontemporal). Phase4 PV split-K: waves 0-3 k-lo, 4-7 k-hi, LDS combine.
__global__ __launch_bounds__(512) void attn_kernel(const u16* __restrict__ Q,
                                                   const u16* __restrict__ K,
                                                   const u16* __restrict__ Vt,
                                                   const int* __restrict__ mask,
                                                   float* __restrict__ attn_out,
                                                   u16* __restrict__ Obuf) {
    __shared__ __align__(16) u16 P[16][2056];   // 65,792 B (+8 pad)
    __shared__ float partial[16][8];
    __shared__ float linv[16];
    __shared__ float ored[4][16][16];           // 4 KB PV k-half combine

    const int tid = threadIdx.x;
    const int lane = tid & 63, wave = tid >> 6;  // 8 waves
    const int q16 = lane & 15, quad = lane >> 4;
    const int qblk = blockIdx.x, h = blockIdx.y, b = blockIdx.z;
    const int qbase = qblk * 16;

    const u16* qplane = Q + (size_t)((b * NH + h) * SL) * HD;
    const u16* kplane = K + (size_t)((b * NH + h) * SL) * HD;

    const u16* qrow = qplane + (qbase + q16) * HD + quad * 8;
    const short8 aq0 = *(const short8*)(qrow);
    const short8 aq1 = *(const short8*)(qrow + 32);

    // ---- Phase 1: S strip -> u = exp(s/8) (masked -> 0) into LDS + reg rowsums ----
    const int qg0 = qbase + quad * 4;                  // q row for r=0
    const int* mbase = mask + (size_t)(b * SL + qg0) * SL;
    const int k0 = wave * 256;
    float rs0 = 0.f, rs1 = 0.f, rs2 = 0.f, rs3 = 0.f;
    #pragma unroll 2
    for (int kt = 0; kt < 16; ++kt) {
        const int kbase = k0 + kt * 16;
        const u16* krow = kplane + (kbase + q16) * HD + quad * 8;
        short8 b0 = *(const short8*)(krow);
        short8 b1 = *(const short8*)(krow + 32);
        f32x4 s = {};
        s = __builtin_amdgcn_mfma_f32_16x16x32_bf16(aq0, b0, s, 0, 0, 0);
        s = __builtin_amdgcn_mfma_f32_16x16x32_bf16(aq1, b1, s, 0, 0, 0);
        const int* mrow = mbase + kbase + q16;
        const float u0 = mrow[0]          ? 0.0f : __expf(s[0] * 0.125f);
        const float u1 = mrow[SL]         ? 0.0f : __expf(s[1] * 0.125f);
        const float u2 = mrow[2 * SL]     ? 0.0f : __expf(s[2] * 0.125f);
        const float u3 = mrow[3 * SL]     ? 0.0f : __expf(s[3] * 0.125f);
        rs0 += u0; rs1 += u1; rs2 += u2; rs3 += u3;
        P[quad * 4 + 0][kbase + q16] = f2bf(u0);
        P[quad * 4 + 1][kbase + q16] = f2bf(u1);
        P[quad * 4 + 2][kbase + q16] = f2bf(u2);
        P[quad * 4 + 3][kbase + q16] = f2bf(u3);
    }
    // reduce row partials over the 16 q16 lanes (stays within each quad)
    #pragma unroll
    for (int off = 1; off < 16; off <<= 1) {
        rs0 += __shfl_xor(rs0, off);
        rs1 += __shfl_xor(rs1, off);
        rs2 += __shfl_xor(rs2, off);
        rs3 += __shfl_xor(rs3, off);
    }
    if (q16 == 0) {
        partial[quad * 4 + 0][wave] = rs0;
        partial[quad * 4 + 1][wave] = rs1;
        partial[quad * 4 + 2][wave] = rs2;
        partial[quad * 4 + 3][wave] = rs3;
    }
    __syncthreads();

    // ---- Phase 2: fold 8 strip-partials per row ----
    if (tid < 16) {
        float s = 0.f;
        #pragma unroll
        for (int w = 0; w < 8; ++w) s += partial[tid][w];
        linv[tid] = 1.0f / s;
    }
    __syncthreads();

    // ---- Phase 3: write normalized attn, fp32, nontemporal ----
    {
        const int r3 = tid >> 5, cseg = tid & 31;
        const float inv = linv[r3];
        const size_t rowbase = ((size_t)((b * NH + h) * SL + qbase + r3)) * SL;
        #pragma unroll
        for (int i = 0; i < 8; ++i) {
            const int c = cseg * 8 + i * 256;
            short8 v = *(const short8*)&P[r3][c];
            f32x4 w0, w1;
            w0[0] = bf2f(((u16*)&v)[0]) * inv;
            w0[1] = bf2f(((u16*)&v)[1]) * inv;
            w0[2] = bf2f(((u16*)&v)[2]) * inv;
            w0[3] = bf2f(((u16*)&v)[3]) * inv;
            w1[0] = bf2f(((u16*)&v)[4]) * inv;
            w1[1] = bf2f(((u16*)&v)[5]) * inv;
            w1[2] = bf2f(((u16*)&v)[6]) * inv;
            w1[3] = bf2f(((u16*)&v)[7]) * inv;
            __builtin_nontemporal_store(w0, (f32x4*)(attn_out + rowbase + c));
            __builtin_nontemporal_store(w1, (f32x4*)(attn_out + rowbase + c + 4));
        }
    }

    // ---- Phase 4: O = P @ V, split-K over wave halves ----
    const int dt = wave & 3, kh = wave >> 2;   // d-tile 0..3, k-half 0/1
    const u16* vplane = Vt + (size_t)((b * NH + h) * HD) * SL;
    f32x4 o = {};
    const int kstart = kh * 1024;
    #pragma unroll 4
    for (int kk = kstart; kk < kstart + 1024; kk += 32) {
        short8 a = *(const short8*)&P[q16][kk + quad * 8];
        short8 bv = *(const short8*)(vplane + (dt * 16 + q16) * SL + kk + quad * 8);
        o = __builtin_amdgcn_mfma_f32_16x16x32_bf16(a, bv, o, 0, 0, 0);
    }
    if (kh == 1) {
        #pragma unroll
        for (int rr = 0; rr < 4; ++rr) ored[dt][quad * 4 + rr][q16] = o[rr];
    }
    __syncthreads();
    if (kh == 0) {
        #pragma unroll
        for (int rr = 0; rr < 4; ++rr) {
            const int row = quad * 4 + rr;
            const float val = (o[rr] + ored[dt][row][q16]) * linv[row];
            const int qg = qbase + row;
            Obuf[(size_t)(b * SL + qg) * DE + h * HD + dt * 16 + q16] = f2bf(val);
        }
    }
}

extern "C" void kernel_launch(void* const* d_in, const int* in_sizes, int n_in,
                              void* d_out, int out_size, void* d_ws, size_t ws_size,
                              hipStream_t stream) {
    const float* x_q = (const float*)d_in[0];
    const float* x_k = (const float*)d_in[1];
    const float* x_v = (const float*)d_in[2];
    const int* mask = (const int*)d_in[3];
    const float* Wq = (const float*)d_in[4];
    const float* bq = (const float*)d_in[5];
    const float* Wk = (const float*)d_in[6];
    const float* bk = (const float*)d_in[7];
    const float* Wv = (const float*)d_in[8];
    const float* bv = (const float*)d_in[9];
    const float* Wo = (const float*)d_in[10];
    const float* bo = (const float*)d_in[11];

    // ws layout: q | k | vt | o_cat, each B*H*L*HD = 4,194,304 bf16 (8 MiB) -> 32 MiB
    u16* ws = (u16*)d_ws;
    u16* qb = ws;
    u16* vt = ws + 2 * 4194304;
    u16* ob = ws + 3 * 4194304;

    float* outp = (float*)d_out;
    float* attn_out = outp + 4194304;  // final is B*L*DE = 4,194,304 elems

    // Scratch for bf16 pre-converted X and W lives in the attn output region:
    // consumed by the QKV gemms (before attn_kernel), then fully overwritten
    // by attn_kernel's real output.
    u16* xbf = (u16*)attn_out;                 // 3 x 4,194,304 u16 (24 MiB)
    u16* wbf = xbf + 3 * 4194304;              // 3 x   262,144 u16 (1.5 MiB)

    cvt3<<<dim3(2048, 3), 256, 0, stream>>>(x_q, x_k, x_v, xbf, 4194304);
    cvt3<<<dim3(128, 3), 256, 0, stream>>>(Wq, Wk, Wv, wbf, 262144);

    // Fused QKV projection: 3072 blocks in one dispatch.
    gemm_qkv<<<dim3(128, 8, 3), 256, 0, stream>>>(xbf, wbf, bq, bk, bv, ws);

    attn_kernel<<<dim3(128, 8, 4), 512, 0, stream>>>(qb, ws + 4194304, vt, mask, attn_out, ob);

    // Wo -> bf16 into the now-dead Q region of ws, then final projection.
    cvt3<<<dim3(128, 1), 256, 0, stream>>>(Wo, Wo, Wo, qb, 262144);
    gemm_fin<<<dim3(128, 8), 256, 0, stream>>>(ob, qb, bo, outp);
}